// Round 1
// baseline (526.521 us; speedup 1.0000x reference)
//
#include <hip/hip_runtime.h>
#include <hip/hip_bf16.h>
#include <math.h>

#define N_NODES 50000
#define N_EDGES 800000
#define F_IN    256
#define HEADS   8
#define C1      32
#define F1      256   // HEADS*C1
#define C2      16
#define NEG     0.2f
#define EPSF    1e-16f

// ---------------- graph build: CSR by dst (self-loops included) -------------

__global__ void k_init_deg(int* __restrict__ deg) {
    int i = blockIdx.x * blockDim.x + threadIdx.x;
    if (i < N_NODES) deg[i] = 1;   // the self-loop
}

__global__ void k_hist(const int* __restrict__ ei, int* __restrict__ deg) {
    int i = blockIdx.x * blockDim.x + threadIdx.x;
    if (i < N_EDGES) atomicAdd(&deg[ei[N_EDGES + i]], 1);
}

// single-block exclusive scan over deg -> offs[N+1], also copies into cursor
__global__ void k_scan(const int* __restrict__ deg, int* __restrict__ offs,
                       int* __restrict__ cursor) {
    __shared__ int wsum[16];
    __shared__ int carry_s;
    int t = threadIdx.x;
    int lane = t & 63;
    int w = t >> 6;
    if (t == 0) carry_s = 0;
    __syncthreads();
    for (int base = 0; base < N_NODES; base += 1024) {
        int idx = base + t;
        int v = (idx < N_NODES) ? deg[idx] : 0;
        int sv = v;
        #pragma unroll
        for (int off = 1; off < 64; off <<= 1) {
            int y = __shfl_up(sv, off, 64);
            if (lane >= off) sv += y;
        }
        __syncthreads();   // protect wsum/carry_s from previous iter readers
        if (lane == 63) wsum[w] = sv;
        __syncthreads();
        if (w == 0) {
            int xx = (lane < 16) ? wsum[lane] : 0;
            #pragma unroll
            for (int off = 1; off < 16; off <<= 1) {
                int y = __shfl_up(xx, off, 64);
                if (lane >= off) xx += y;
            }
            if (lane < 16) wsum[lane] = xx;   // inclusive scan of wave sums
        }
        __syncthreads();
        int carry = carry_s;
        int waveoff = (w == 0) ? 0 : wsum[w - 1];
        int exc = carry + waveoff + sv - v;
        if (idx < N_NODES) { offs[idx] = exc; cursor[idx] = exc; }
        __syncthreads();
        if (t == 1023) carry_s = carry + wsum[15];
    }
    __syncthreads();
    if (t == 0) offs[N_NODES] = carry_s;
}

__global__ void k_scatter(const int* __restrict__ ei, int* __restrict__ cursor,
                          int* __restrict__ ssrc) {
    int i = blockIdx.x * blockDim.x + threadIdx.x;
    const int total = N_EDGES + N_NODES;
    if (i >= total) return;
    int s, d;
    if (i < N_EDGES) { s = ei[i]; d = ei[N_EDGES + i]; }
    else             { s = d = i - N_EDGES; }
    int p = atomicAdd(&cursor[d], 1);
    ssrc[p] = s;
}

// ---------------- layer 1 GEMM: h1 = x @ W1, plus al_src/al_dst -------------
// block = 256 threads computes a 32-row x 256-col tile.
// thread t: cg = t&63 -> cols 4*cg..4*cg+3 ; rg = t>>6 -> rows rg*8..rg*8+7
__global__ __launch_bounds__(256) void k_gemm1(
        const float* __restrict__ x,  const float* __restrict__ W1,
        const float* __restrict__ as1, const float* __restrict__ ad1,
        float* __restrict__ h1, float* __restrict__ als, float* __restrict__ ald) {
    __shared__ float xsT[256 * 36];   // k-major, padded: row r at xsT[k*36+r]
    int t = threadIdx.x;
    int cg = t & 63, rg = t >> 6;
    int row0 = blockIdx.x * 32;

    for (int it = 0; it < 32; ++it) {
        int row = row0 + it;
        float v = (row < N_NODES) ? x[row * F_IN + t] : 0.0f;
        xsT[t * 36 + it] = v;
    }
    __syncthreads();

    float4 acc[8];
    #pragma unroll
    for (int r = 0; r < 8; ++r) acc[r] = make_float4(0.f, 0.f, 0.f, 0.f);

    const float* wp = W1 + (cg << 2);
    int r0 = rg * 8;
    for (int k = 0; k < 256; ++k) {
        float4 w4 = *(const float4*)(wp + (k << 8));
        const float* xp = &xsT[k * 36 + r0];
        #pragma unroll
        for (int r = 0; r < 8; ++r) {
            float xv = xp[r];
            acc[r].x += xv * w4.x; acc[r].y += xv * w4.y;
            acc[r].z += xv * w4.z; acc[r].w += xv * w4.w;
        }
    }

    float4 as4 = *(const float4*)(as1 + (cg << 2));
    float4 ad4 = *(const float4*)(ad1 + (cg << 2));
    int h = cg >> 3;
    #pragma unroll
    for (int r = 0; r < 8; ++r) {
        int row = row0 + r0 + r;
        if (row < N_NODES)
            *(float4*)(h1 + (size_t)row * F1 + (cg << 2)) = acc[r];
        float vs = acc[r].x * as4.x + acc[r].y * as4.y + acc[r].z * as4.z + acc[r].w * as4.w;
        float vd = acc[r].x * ad4.x + acc[r].y * ad4.y + acc[r].z * ad4.z + acc[r].w * ad4.w;
        #pragma unroll
        for (int m = 1; m < 8; m <<= 1) {
            vs += __shfl_xor(vs, m, 64);
            vd += __shfl_xor(vd, m, 64);
        }
        if ((cg & 7) == 0 && row < N_NODES) {
            als[row * HEADS + h] = vs;
            ald[row * HEADS + h] = vd;
        }
    }
}

// ------------- layer 1 aggregation (softmax + weighted sum + ELU) ----------
// one block of 256 threads per dst node; thread t = output channel t.
__global__ __launch_bounds__(256) void k_agg1(
        const int* __restrict__ offs, const int* __restrict__ ssrc,
        const float* __restrict__ h1, const float* __restrict__ als,
        const float* __restrict__ ald, const float* __restrict__ b1,
        float* __restrict__ hpost) {
    __shared__ int   s_lds[64];
    __shared__ float w_lds[64 * 8];
    __shared__ float denom[8];
    __shared__ float aldi[8];
    int t = threadIdx.x;
    int i = blockIdx.x;
    if (t < 8) { denom[t] = 0.0f; aldi[t] = ald[i * HEADS + t]; }
    int beg = offs[i], end = offs[i + 1];
    float acc = 0.0f;
    int hc = t >> 5;
    for (int c0 = beg; c0 < end; c0 += 64) {
        int nc = min(64, end - c0);
        __syncthreads();                 // prev chunk readers done
        if (t < nc) s_lds[t] = ssrc[c0 + t];
        __syncthreads();
        for (int it = t; it < nc * 8; it += 256) {
            int e = it >> 3, hh = it & 7;
            int s = s_lds[e];
            float v = als[s * HEADS + hh] + aldi[hh];
            v = (v > 0.0f) ? v : NEG * v;
            float wv = __expf(v);
            w_lds[it] = wv;
            atomicAdd(&denom[hh], wv);
        }
        __syncthreads();
        for (int e = 0; e < nc; ++e)
            acc += w_lds[e * 8 + hc] * h1[(size_t)s_lds[e] * F1 + t];
    }
    __syncthreads();
    float val = acc / (denom[hc] + EPSF) + b1[t];
    val = (val > 0.0f) ? val : (__expf(val) - 1.0f);   // ELU
    hpost[(size_t)i * F1 + t] = val;
}

// ---------------- layer 2 GEMM: h2 = hpost @ W2, plus al2 ------------------
// block = 256 threads = 16 rows x 16 cols
__global__ __launch_bounds__(256) void k_gemm2(
        const float* __restrict__ hpost, const float* __restrict__ W2,
        const float* __restrict__ as2, const float* __restrict__ ad2,
        float* __restrict__ h2, float* __restrict__ als2, float* __restrict__ ald2) {
    __shared__ float xs[16 * 257];
    __shared__ float w2s[256 * 16];
    int t = threadIdx.x;
    int row0 = blockIdx.x * 16;
    for (int it = 0; it < 16; ++it) {
        xs[it * 257 + t] = hpost[(size_t)(row0 + it) * F1 + t];
        w2s[it * 256 + t] = W2[it * 256 + t];
    }
    __syncthreads();
    int r = t >> 4, c = t & 15;
    float acc = 0.0f;
    for (int k = 0; k < 256; ++k)
        acc += xs[r * 257 + k] * w2s[k * 16 + c];
    int row = row0 + r;
    h2[row * C2 + c] = acc;
    float vs = acc * as2[c];
    float vd = acc * ad2[c];
    #pragma unroll
    for (int m = 1; m < 16; m <<= 1) {
        vs += __shfl_xor(vs, m, 64);
        vd += __shfl_xor(vd, m, 64);
    }
    if (c == 0) { als2[row] = vs; ald2[row] = vd; }
}

// ---------------- layer 2 aggregation -> out -------------------------------
// one wave (64 threads) per dst node. c = t&15 channel, es = t>>4 edge-slice.
__global__ __launch_bounds__(64) void k_agg2(
        const int* __restrict__ offs, const int* __restrict__ ssrc,
        const float* __restrict__ h2, const float* __restrict__ als2,
        const float* __restrict__ ald2, const float* __restrict__ b2,
        float* __restrict__ out) {
    __shared__ int   s_lds[64];
    __shared__ float w_lds[64];
    int t = threadIdx.x;
    int i = blockIdx.x;
    float adi = ald2[i];
    int beg = offs[i], end = offs[i + 1];
    float acc = 0.0f, dsum = 0.0f;
    int c = t & 15, es = t >> 4;
    for (int c0 = beg; c0 < end; c0 += 64) {
        int nc = min(64, end - c0);
        __syncthreads();
        if (t < nc) {
            int s = ssrc[c0 + t];
            s_lds[t] = s;
            float v = als2[s] + adi;
            v = (v > 0.0f) ? v : NEG * v;
            float wv = __expf(v);
            w_lds[t] = wv;
            dsum += wv;
        }
        __syncthreads();
        for (int e = es; e < nc; e += 4)
            acc += w_lds[e] * h2[s_lds[e] * C2 + c];
    }
    #pragma unroll
    for (int m = 1; m < 64; m <<= 1) dsum += __shfl_xor(dsum, m, 64);
    acc += __shfl_xor(acc, 16, 64);
    acc += __shfl_xor(acc, 32, 64);
    if (t < 16) out[i * C2 + t] = acc / (dsum + EPSF) + b2[t];
}

// ---------------------------------------------------------------------------

extern "C" void kernel_launch(void* const* d_in, const int* in_sizes, int n_in,
                              void* d_out, int out_size, void* d_ws, size_t ws_size,
                              hipStream_t stream) {
    const float* x   = (const float*)d_in[0];
    const int*   ei  = (const int*)d_in[1];
    const float* W1  = (const float*)d_in[2];
    const float* as1 = (const float*)d_in[3];
    const float* ad1 = (const float*)d_in[4];
    const float* b1  = (const float*)d_in[5];
    const float* W2  = (const float*)d_in[6];
    const float* as2 = (const float*)d_in[7];
    const float* ad2 = (const float*)d_in[8];
    const float* b2  = (const float*)d_in[9];
    float* out = (float*)d_out;

    char* ws = (char*)d_ws;
    size_t off = 0;
    auto alloc = [&](size_t bytes) {
        off = (off + 255) & ~(size_t)255;
        void* p = ws + off;
        off += bytes;
        return p;
    };
    float* h1    = (float*)alloc((size_t)N_NODES * F1 * 4);
    float* hpost = (float*)alloc((size_t)N_NODES * F1 * 4);
    float* als   = (float*)alloc((size_t)N_NODES * HEADS * 4);
    float* ald   = (float*)alloc((size_t)N_NODES * HEADS * 4);
    float* h2    = (float*)alloc((size_t)N_NODES * C2 * 4);
    float* als2  = (float*)alloc((size_t)N_NODES * 4);
    float* ald2  = (float*)alloc((size_t)N_NODES * 4);
    int*   deg   = (int*)alloc((size_t)N_NODES * 4);
    int*   offs  = (int*)alloc((size_t)(N_NODES + 1) * 4);
    int*   cursor= (int*)alloc((size_t)N_NODES * 4);
    int*   ssrc  = (int*)alloc((size_t)(N_EDGES + N_NODES) * 4);
    (void)ws_size; (void)in_sizes; (void)n_in; (void)out_size;

    k_init_deg<<<(N_NODES + 255) / 256, 256, 0, stream>>>(deg);
    k_hist<<<(N_EDGES + 255) / 256, 256, 0, stream>>>(ei, deg);
    k_scan<<<1, 1024, 0, stream>>>(deg, offs, cursor);
    k_scatter<<<(N_EDGES + N_NODES + 255) / 256, 256, 0, stream>>>(ei, cursor, ssrc);
    k_gemm1<<<(N_NODES + 31) / 32, 256, 0, stream>>>(x, W1, as1, ad1, h1, als, ald);
    k_agg1<<<N_NODES, 256, 0, stream>>>(offs, ssrc, h1, als, ald, b1, hpost);
    k_gemm2<<<N_NODES / 16, 256, 0, stream>>>(hpost, W2, as2, ad2, h2, als2, ald2);
    k_agg2<<<N_NODES, 64, 0, stream>>>(offs, ssrc, h2, als2, ald2, b2, out);
}